// Round 10
// baseline (697.155 us; speedup 1.0000x reference)
//
#include <hip/hip_runtime.h>

using u16 = unsigned short;
using u32 = unsigned int;

typedef __attribute__((ext_vector_type(8))) short bf16x8;
typedef __attribute__((ext_vector_type(4))) float f32x4;

#define NTOK 16384

// ---------------- workspace layout (bytes) ----------------
constexpr size_t OFF_FLAG   = 0;         // f32-mode flag
constexpr size_t OFF_FCNT   = 256;       // flagged-token count
constexpr size_t OFF_M      = 512;       // 1024 f64 slot_mean
constexpr size_t OFF_B1P64  = 8704;      // 512 f64
constexpr size_t OFF_B1P32  = 12800;     // 512 f32
constexpr size_t OFF_B2F    = 14848;     // 64 f32
constexpr size_t OFF_BIHF   = 15104;     // 3072 f32
constexpr size_t OFF_BHHF   = 27392;     // 3072 f32
constexpr size_t OFF_BVF    = 39680;     // 1024 f32
constexpr size_t OFF_BOF    = 43776;     // 1024 f32
constexpr size_t OFF_FLAGS  = 47872;     // 16384 int
constexpr size_t OFF_HSHI   = 113408;    // 64*1024 u16
constexpr size_t OFF_HSLO   = 244480;
constexpr size_t OFF_HSF    = 375552;    // 64*1024 f32
constexpr size_t OFF_GH     = 637696;    // 64*3072 f32
constexpr size_t OFF_GIHI   = 1424128;   // 256*1024 u16
constexpr size_t OFF_GILO   = 1948416;
constexpr size_t OFF_GX     = 2472704;   // 256*3072 f32
constexpr size_t OFF_SNHI   = 5618432;   // 256*1024 u16
constexpr size_t OFF_SNLO   = 6142720;
constexpr size_t OFF_SVHI   = 6667008;   // 256*1024 u16
constexpr size_t OFF_SVLO   = 7191296;
constexpr size_t OFF_SVO    = 7715584;   // 256*1024 f32
constexpr size_t OFF_IDX    = 8764160;   // 16384*8 int
constexpr size_t OFF_WGT    = 9288448;   // 16384*8 f32
constexpr size_t OFF_LOGITS = 9812736;   // 16384*64 f32
constexpr size_t OFF_W1HI   = 14007040;  // 512*2048 u16
constexpr size_t OFF_W1LO   = 16104192;
constexpr size_t OFF_W2HI   = 18201344;  // 64*512 u16
constexpr size_t OFF_W2LO   = 18266880;
constexpr size_t OFF_WIHHI  = 18332416;  // 3072*1024 u16
constexpr size_t OFF_WIHLO  = 24623872;
constexpr size_t OFF_WHHHI  = 30915328;
constexpr size_t OFF_WHHLO  = 37206784;
constexpr size_t OFF_WVHI   = 43498240;  // 1024*1024 u16
constexpr size_t OFF_WVLO   = 45595392;
constexpr size_t OFF_WOHI   = 47692544;
constexpr size_t OFF_WOLO   = 49789696;
constexpr size_t OFF_HHI    = 51886848;  // 16384*512 u16
constexpr size_t OFF_HLO    = 68664064;
constexpr size_t OFF_DPART  = 85441280;  // 256*8*1024 f32 dispatch partials
constexpr size_t OFF_DWSUM  = 93829888;  // 256*8 f32 weight-sum partials
constexpr size_t OFF_HSMG   = 93838080;  // 256*512 f64 repair hidden rows
constexpr size_t WS_NEED    = 94886656;  // < 101,169,920 proven available r2

constexpr int QCAP = 256;                // fast-path repair token capacity

// ---------------- helpers ----------------
__device__ __forceinline__ float bf2f(u16 u) {
  union { u32 i; float f; } c; c.i = ((u32)u) << 16; return c.f;
}
__device__ __forceinline__ u16 f2bf(float f) {  // RNE
  u32 x = __float_as_uint(f);
  x += 0x7fffu + ((x >> 16) & 1u);
  return (u16)(x >> 16);
}
__device__ __forceinline__ void splitf(float v, u16& hi, u16& lo) {
  hi = f2bf(v);
  lo = f2bf(v - bf2f(hi));
}
__device__ __forceinline__ float rdval(const void* p, int i, int f32m) {
  return f32m ? ((const float*)p)[i] : bf2f(((const u16*)p)[i]);
}
__device__ __forceinline__ void async16(const u16* g, u16* l) {
  __builtin_amdgcn_global_load_lds((const __attribute__((address_space(1))) void*)g,
                                   (__attribute__((address_space(3))) void*)l, 16, 0, 0);
}

// ---------------- dtype sniffer (f32 vs bf16 input buffers) ----------------
__global__ void k_sniff(const u32* __restrict__ w1w, int* __restrict__ flag) {
  int t = threadIdx.x;
  u32 word = w1w[t * 97];
  int ef = (word >> 7) & 0xFF;                 // exp field of low u16 as bf16
  unsigned long long m = __ballot(ef >= 128);  // |v|>=2 impossible for bf16 wts
  if (t == 0) flag[0] = (__popcll(m) >= 8) ? 1 : 0;
}

// ---------------- batched conversions (one launch) --------------
// bf16 mode (r10): hi = raw copy, SKIP zero lo-writes -- weight lo-planes
// are identically zero and (with pass-skip GEMMs) never read.
__global__ __launch_bounds__(256) void k_cvt_all(
    const void* __restrict__ w1, const void* __restrict__ w2,
    const void* __restrict__ wih, const void* __restrict__ whh,
    const void* __restrict__ wv, const void* __restrict__ wo,
    const void* __restrict__ b2, const void* __restrict__ bih,
    const void* __restrict__ bhh, const void* __restrict__ bv,
    const void* __restrict__ bo, char* __restrict__ ws,
    const int* __restrict__ flagp)
{
  const int f = *flagp;
  const long long gid = (long long)blockIdx.x * 256 + threadIdx.x;
  const long long C0 = 1048576, C1 = C0 + 32768, C2 = C1 + 3145728,
                  C3 = C2 + 3145728, C4 = C3 + 1048576, C5 = C4 + 1048576;
  if (gid < C5) {
    const void* src; size_t oh, ol; int i;
    if (gid < C0)      { src = w1;  oh = OFF_W1HI;  ol = OFF_W1LO;  i = (int)gid; }
    else if (gid < C1) { src = w2;  oh = OFF_W2HI;  ol = OFF_W2LO;  i = (int)(gid - C0); }
    else if (gid < C2) { src = wih; oh = OFF_WIHHI; ol = OFF_WIHLO; i = (int)(gid - C1); }
    else if (gid < C3) { src = whh; oh = OFF_WHHHI; ol = OFF_WHHLO; i = (int)(gid - C2); }
    else if (gid < C4) { src = wv;  oh = OFF_WVHI;  ol = OFF_WVLO;  i = (int)(gid - C3); }
    else               { src = wo;  oh = OFF_WOHI;  ol = OFF_WOLO;  i = (int)(gid - C4); }
    if (f) {
      float v = ((const float*)src)[i];
      u16 hi, lo; splitf(v, hi, lo);
      ((u16*)(ws + oh))[i] = hi;
      ((u16*)(ws + ol))[i] = lo;
    } else {
      ((u16*)(ws + oh))[i] = ((const u16*)src)[i];  // lo plane unused
    }
    return;
  }
  int r = (int)(gid - C5);
  if (r >= 8256) return;
  const void* src; size_t od; int i;
  if (r < 64)        { src = b2;  od = OFF_B2F;  i = r; }
  else if (r < 3136) { src = bih; od = OFF_BIHF; i = r - 64; }
  else if (r < 6208) { src = bhh; od = OFF_BHHF; i = r - 3136; }
  else if (r < 7232) { src = bv;  od = OFF_BVF;  i = r - 6208; }
  else               { src = bo;  od = OFF_BOF;  i = r - 7232; }
  ((float*)(ws + od))[i] = rdval(src, i, f);
}

// ---------------- bt-GEMM: C[M,N] = A[M,K] @ B[N,K]^T ----------------
// r7 structure. r10: pass count is mode-dependent. B is ALWAYS a weight
// matrix here; in bf16 mode its lo-plane is identically zero, so the
// Ahi*Blo pass (sp==2) multiplies zeros -- skip it: PASSES = f32m ? 3 : 2.
// (A-side lo is f32-intermediate split, nonzero in both modes -> keep sp==1.)
// MODE 0: f32 out. MODE 3: split-bf16 out.
template<int MODE>
__global__ __launch_bounds__(512, 2) void gemm_bt(
    const u16* __restrict__ Ahi, const u16* __restrict__ Alo,
    const u16* __restrict__ Bhi, const u16* __restrict__ Blo,
    int M, int N, int K, int ldb,
    const float* __restrict__ biasF, float* __restrict__ outF,
    u16* __restrict__ outHi, u16* __restrict__ outLo,
    const int* __restrict__ flagp)
{
  __shared__ alignas(16) u16 smem[2 * 2 * 8192];  // [grp][buf][At 4096|Bt 4096]
  const int f32m = *flagp;
  const int t    = threadIdx.x;
  const int grp  = t >> 8;
  const int tl   = t & 255;
  const int wvid = tl >> 6;
  const int lane = t & 63;
  const int quad = lane >> 4;
  const int l16  = lane & 15;
  const int row0 = blockIdx.x * 128;
  const int col0 = blockIdx.y * 128;
  const int wr   = (wvid >> 1) * 64;
  const int wc   = (wvid & 1) * 64;

  const int ra  = tl >> 2;
  const int kqe = (tl & 3) * 8;
  int r_a0 = row0 + ra;      if (r_a0 > M - 1) r_a0 = M - 1;
  int r_a1 = row0 + ra + 64; if (r_a1 > M - 1) r_a1 = M - 1;
  int r_b0 = col0 + ra;      if (r_b0 > N - 1) r_b0 = N - 1;
  int r_b1 = col0 + ra + 64; if (r_b1 > N - 1) r_b1 = N - 1;
  const size_t aoff0 = (size_t)r_a0 * K + kqe;
  const size_t aoff1 = (size_t)r_a1 * K + kqe;
  const size_t boff0 = (size_t)r_b0 * ldb + kqe;
  const size_t boff1 = (size_t)r_b1 * ldb + kqe;

  const int KH  = K >> 1;             // per-group K range
  const int NIT = (f32m ? 3 : 2) * (KH >> 5);   // passes x KH/32 steps
  int sp = 0, sk = grp * KH;          // stage cursors (pass, k-offset)
  const int skend = grp * KH + KH;

  u16* const base = smem + grp * 16384;
  auto stage = [&](int buf) {
    const u16* Ap = (sp == 1) ? Alo : Ahi;
    const u16* Bp = (sp == 2) ? Blo : Bhi;
    u16* At = base + buf * 8192;
    u16* Bt = At + 4096;
    async16(Ap + aoff0 + sk, &At[(wvid * 64) * 8]);
    async16(Ap + aoff1 + sk, &At[(wvid * 64 + 256) * 8]);
    async16(Bp + boff0 + sk, &Bt[(wvid * 64) * 8]);
    async16(Bp + boff1 + sk, &Bt[(wvid * 64 + 256) * 8]);
    sk += 32;
    if (sk == skend) { sk = grp * KH; ++sp; }
  };

  f32x4 acc[4][4] = {};
  stage(0);
  asm volatile("s_waitcnt vmcnt(0)" ::: "memory");
  __syncthreads();
  int cur = 0;
  for (int it = 0; it < NIT; ++it) {
    if (it + 1 < NIT) stage(cur ^ 1);   // prefetch next K-step into other buf
    const u16* At = base + cur * 8192;
    const u16* Bt = At + 4096;
    bf16x8 af[4], bfr[4];
    #pragma unroll
    for (int mt = 0; mt < 4; ++mt)
      af[mt] = *(const bf16x8*)&At[(wr + mt * 16 + l16) * 32 + quad * 8];
    #pragma unroll
    for (int nt = 0; nt < 4; ++nt)
      bfr[nt] = *(const bf16x8*)&Bt[(wc + nt * 16 + l16) * 32 + quad * 8];
    #pragma unroll
    for (int mt = 0; mt < 4; ++mt)
      #pragma unroll
      for (int nt = 0; nt < 4; ++nt)
        acc[mt][nt] = __builtin_amdgcn_mfma_f32_16x16x32_bf16(
            af[mt], bfr[nt], acc[mt][nt], 0, 0, 0);
    asm volatile("s_waitcnt vmcnt(0)" ::: "memory");
    __syncthreads();
    cur ^= 1;
  }

  // fold: group1 partial -> group0, two wc-halves via 128x64 f32 LDS tile
  float* red = (float*)smem;            // 32 KB, staging dead after loop
  #pragma unroll 1
  for (int half = 0; half < 2; ++half) {
    if (grp == 1 && (wvid & 1) == half) {
      #pragma unroll
      for (int mt = 0; mt < 4; ++mt)
        #pragma unroll
        for (int nt = 0; nt < 4; ++nt)
          #pragma unroll
          for (int r2 = 0; r2 < 4; ++r2)
            red[(wr + mt * 16 + quad * 4 + r2) * 64 + nt * 16 + l16] =
                acc[mt][nt][r2];
    }
    __syncthreads();
    if (grp == 0 && (wvid & 1) == half) {
      #pragma unroll
      for (int mt = 0; mt < 4; ++mt)
        #pragma unroll
        for (int nt = 0; nt < 4; ++nt)
          #pragma unroll
          for (int r2 = 0; r2 < 4; ++r2)
            acc[mt][nt][r2] +=
                red[(wr + mt * 16 + quad * 4 + r2) * 64 + nt * 16 + l16];
    }
    __syncthreads();
  }
  if (grp != 0) return;

  #pragma unroll
  for (int mt = 0; mt < 4; ++mt) {
    #pragma unroll
    for (int nt = 0; nt < 4; ++nt) {
      const int col = col0 + wc + nt * 16 + l16;
      if (col >= N) continue;
      #pragma unroll
      for (int r2 = 0; r2 < 4; ++r2) {
        const int row = row0 + wr + mt * 16 + quad * 4 + r2;
        if (row >= M) continue;
        float v = acc[mt][nt][r2] + biasF[col];
        size_t idx = (size_t)row * N + col;
        if constexpr (MODE == 0) {
          outF[idx] = v;
        } else {
          u16 hi, lo; splitf(v, hi, lo);
          outHi[idx] = hi; outLo[idx] = lo;
        }
      }
    }
  }
}

// ---------------- router GEMM: h = gelu(x @ w1a^T + b1'), x split on the fly
// r7 structure (scalar splitf, single-buffer B, vmcnt(0)+__syncthreads,
// T14 x-register-prefetch). r10: in bf16 mode BOTH lo-planes are exactly
// zero (x is bf16-native, w1 is bf16-native) -> run ONE MFMA pass instead
// of three, skip Blo async loads and Atlo stores entirely.
__global__ __launch_bounds__(256, 4) void gemm_router(
    const void* __restrict__ X,
    const u16* __restrict__ Bhi, const u16* __restrict__ Blo,
    int M, int N, int K, int ldb, const float* __restrict__ biasF,
    u16* __restrict__ outHi, u16* __restrict__ outLo,
    const int* __restrict__ flagp)
{
  __shared__ alignas(16) u16 Athi[64 * 32];
  __shared__ alignas(16) u16 Atlo[64 * 32];
  __shared__ alignas(16) u16 Bthi[128 * 32];
  __shared__ alignas(16) u16 Btlo[128 * 32];
  const int f32m = *flagp;
  const int t    = threadIdx.x;
  const int wvid = t >> 6;
  const int lane = t & 63;
  const int quad = lane >> 4;
  const int l16  = lane & 15;
  const int row0 = blockIdx.x * 64;
  const int col0 = blockIdx.y * 128;
  const int wr   = (wvid >> 1) * 32;     // wave covers 32 rows x 64 cols
  const int wc   = (wvid & 1) * 64;

  const int ra  = t >> 2;
  const int kqe = (t & 3) * 8;
  int r_b0 = col0 + ra;      if (r_b0 > N - 1) r_b0 = N - 1;
  int r_b1 = col0 + ra + 64; if (r_b1 > N - 1) r_b1 = N - 1;
  const u16* gBhi0 = Bhi + (size_t)r_b0 * ldb + kqe;
  const u16* gBhi1 = Bhi + (size_t)r_b1 * ldb + kqe;
  const u16* gBlo0 = Blo + (size_t)r_b0 * ldb + kqe;
  const u16* gBlo1 = Blo + (size_t)r_b1 * ldb + kqe;

  // fixed per-thread A-stage source/dest (row,kq constant across k-steps)
  const float* xsf[2];
  const u16*   xsb[2];
  u16 *adh[2], *adl[2];
  #pragma unroll
  for (int i = 0; i < 2; ++i) {
    int j = t + 256 * i;
    int row = j >> 3, kq = (j & 7) * 4;
    int grow = row0 + row; if (grow > M - 1) grow = M - 1;
    xsf[i] = (const float*)X + (size_t)grow * K + kq;
    xsb[i] = (const u16*)X + (size_t)grow * K + kq;
    adh[i] = &Athi[row * 32 + kq];
    adl[i] = &Atlo[row * 32 + kq];
  }

  f32x4 acc[2][4] = {};
  float4  xv0, xv1;   // prefetched x (f32 mode)
  ushort4 xb0, xb1;   // prefetched x (bf16 mode)
  if (f32m) { xv0 = *(const float4*)xsf[0];  xv1 = *(const float4*)xsf[1]; }
  else      { xb0 = *(const ushort4*)xsb[0]; xb1 = *(const ushort4*)xsb[1]; }

  for (int k0 = 0; k0 < K; k0 += 32) {
    async16(gBhi0 + k0, &Bthi[(wvid * 64) * 8]);
    async16(gBhi1 + k0, &Bthi[(wvid * 64 + 256) * 8]);
    if (f32m) {
      async16(gBlo0 + k0, &Btlo[(wvid * 64) * 8]);
      async16(gBlo1 + k0, &Btlo[(wvid * 64 + 256) * 8]);
    }
    // ---- stage prefetched x(k0) regs -> LDS (no load latency on path) ----
    if (f32m) {
      ushort4 hi4, lo4;
      splitf(xv0.x, hi4.x, lo4.x);
      splitf(xv0.y, hi4.y, lo4.y);
      splitf(xv0.z, hi4.z, lo4.z);
      splitf(xv0.w, hi4.w, lo4.w);
      *(ushort4*)adh[0] = hi4;
      *(ushort4*)adl[0] = lo4;
      splitf(xv1.x, hi4.x, lo4.x);
      splitf(xv1.y, hi4.y, lo4.y);
      splitf(xv1.z, hi4.z, lo4.z);
      splitf(xv1.w, hi4.w, lo4.w);
      *(ushort4*)adh[1] = hi4;
      *(ushort4*)adl[1] = lo4;
    } else {
      *(ushort4*)adh[0] = xb0;
      *(ushort4*)adh[1] = xb1;
    }
    // ---- issue x(k0+32) prefetch; flies during B-drain + barriers ----
    if (k0 + 32 < K) {
      if (f32m) {
        xv0 = *(const float4*)(xsf[0] + k0 + 32);
        xv1 = *(const float4*)(xsf[1] + k0 + 32);
      } else {
        xb0 = *(const ushort4*)(xsb[0] + k0 + 32);
        xb1 = *(const ushort4*)(xsb[1] + k0 + 32);
      }
    }
    asm volatile("s_waitcnt vmcnt(0)" ::: "memory");
    __syncthreads();
    bf16x8 ah[2], bh[4];
    #pragma unroll
    for (int mt = 0; mt < 2; ++mt)
      ah[mt] = *(const bf16x8*)&Athi[(wr + mt * 16 + l16) * 32 + quad * 8];
    #pragma unroll
    for (int nt = 0; nt < 4; ++nt)
      bh[nt] = *(const bf16x8*)&Bthi[(wc + nt * 16 + l16) * 32 + quad * 8];
    if (f32m) {
      bf16x8 al[2], bl[4];
      #pragma unroll
      for (int mt = 0; mt < 2; ++mt)
        al[mt] = *(const bf16x8*)&Atlo[(wr + mt * 16 + l16) * 32 + quad * 8];
      #pragma unroll
      for (int nt = 0; nt < 4; ++nt)
        bl[nt] = *(const bf16x8*)&Btlo[(wc + nt * 16 + l16) * 32 + quad * 8];
      #pragma unroll
      for (int mt = 0; mt < 2; ++mt)
        #pragma unroll
        for (int nt = 0; nt < 4; ++nt) {
          acc[mt][nt] = __builtin_amdgcn_mfma_f32_16x16x32_bf16(
              ah[mt], bh[nt], acc[mt][nt], 0, 0, 0);
          acc[mt][nt] = __builtin_amdgcn_mfma_f32_16x16x32_bf16(
              al[mt], bh[nt], acc[mt][nt], 0, 0, 0);
          acc[mt][nt] = __builtin_amdgcn_mfma_f32_16x16x32_bf16(
              ah[mt], bl[nt], acc[mt][nt], 0, 0, 0);
        }
    } else {
      #pragma unroll
      for (int mt = 0; mt < 2; ++mt)
        #pragma unroll
        for (int nt = 0; nt < 4; ++nt)
          acc[mt][nt] = __builtin_amdgcn_mfma_f32_16x16x32_bf16(
              ah[mt], bh[nt], acc[mt][nt], 0, 0, 0);
    }
    __syncthreads();
  }

  #pragma unroll
  for (int mt = 0; mt < 2; ++mt) {
    #pragma unroll
    for (int nt = 0; nt < 4; ++nt) {
      const int col = col0 + wc + nt * 16 + l16;
      if (col >= N) continue;
      #pragma unroll
      for (int r2 = 0; r2 < 4; ++r2) {
        const int row = row0 + wr + mt * 16 + quad * 4 + r2;
        if (row >= M) continue;
        float v = acc[mt][nt][r2] + biasF[col];
        v = 0.5f * v * (1.0f + erff(v * 0.70710678118654752f));
        u16 hi, lo; splitf(v, hi, lo);
        size_t idx = (size_t)row * N + col;
        outHi[idx] = hi; outLo[idx] = lo;
      }
    }
  }
}

// ---------------- init: fcnt=0, slot_mean f64, hs split + f32 ----------------
__global__ __launch_bounds__(256) void k_init(const void* __restrict__ sli,
    const void* __restrict__ slsc, const int* __restrict__ flagp,
    double* __restrict__ m64, int* __restrict__ fcnt,
    u16* __restrict__ hshi, u16* __restrict__ hslo, float* __restrict__ hsf)
{
  int f = *flagp;
  int gid = blockIdx.x * 256 + threadIdx.x;
  if (gid == 0) fcnt[0] = 0;
  if (gid < 1024) {
    double s = 0.0;
    for (int j = 0; j < 64; ++j)
      s += (double)rdval(sli, j * 1024 + gid, f) * (double)rdval(slsc, j, f);
    m64[gid] = s * (1.0 / 64.0);
  }
  for (int i = gid; i < 64 * 1024; i += 16384) {
    int s = i >> 10;
    float v = rdval(sli, i, f) * rdval(slsc, s, f);
    splitf(v, hshi[i], hslo[i]);
    hsf[i] = v;
  }
}

// b1' = b1 + w1[:,1024:2048] @ slot_mean   (f64)
__global__ __launch_bounds__(256) void k_b1p(const void* __restrict__ w1,
    const void* __restrict__ b1, const int* __restrict__ flagp,
    const double* __restrict__ m64, double* __restrict__ b1p64,
    float* __restrict__ b1p32)
{
  int f = *flagp;
  int h = blockIdx.x * 256 + threadIdx.x;
  if (h >= 512) return;
  double a = (double)rdval(b1, h, f);
  if (f) {
    const float* wr = (const float*)w1 + (size_t)h * 2048 + 1024;
    for (int d = 0; d < 1024; ++d) a += (double)wr[d] * m64[d];
  } else {
    const u16* wr = (const u16*)w1 + (size_t)h * 2048 + 1024;
    for (int d = 0; d < 1024; ++d) a += (double)bf2f(wr[d]) * m64[d];
  }
  b1p64[h] = a;
  b1p32[h] = (float)a;
}

// ---------------- top-k per token (wave = token) ----------------
__global__ __launch_bounds__(256) void k_topk(const float* __restrict__ logits,
    const void* __restrict__ tau, const int* __restrict__ flagp,
    int* __restrict__ idxb, float* __restrict__ wgtb,
    int* __restrict__ fcnt, int* __restrict__ flags)
{
  const int f32m = *flagp;
  const int n    = blockIdx.x * 4 + (threadIdx.x >> 6);
  const int lane = threadIdx.x & 63;
  float cur = logits[(size_t)n * 64 + lane];
  float tv[8]; int ti[8]; float v9 = 0.f;
  #pragma unroll
  for (int it = 0; it < 9; ++it) {
    float v = cur; int i = lane;
    #pragma unroll
    for (int off = 32; off; off >>= 1) {   // xor-butterfly argmax, tie -> min idx
      float ov = __shfl_xor(v, off);
      int   oi = __shfl_xor(i, off);
      if (ov > v || (ov == v && oi < i)) { v = ov; i = oi; }
    }
    if (it < 8) { tv[it] = v; ti[it] = i; if (lane == i) cur = -__builtin_inff(); }
    else v9 = v;
  }
  float itau = 1.0f / (fabsf(rdval(tau, 0, f32m)) + 0.1f);
  float e[8], z = 0.f;
  #pragma unroll
  for (int k = 0; k < 8; ++k) { e[k] = expf((tv[k] - tv[0]) * itau); z += e[k]; }
  if (lane == 0) {
    float theta = f32m ? 2e-4f : 1e-4f;   // 18+ sigma above logit noise
    if (tv[7] - v9 < theta) { int p = atomicAdd(fcnt, 1); flags[p] = n; }
    float rz = 1.0f / z;
    #pragma unroll
    for (int k = 0; k < 8; ++k) {
      idxb[n * 8 + k] = ti[k];
      wgtb[n * 8 + k] = e[k] * rz;
    }
  }
}

// ---------------- f64 re-route of flagged tokens, stage 1 ----------------
__global__ __launch_bounds__(256) void k_repair_h(const void* __restrict__ x,
    const void* __restrict__ w1, const int* __restrict__ flagp,
    const double* __restrict__ b1p64, const int* __restrict__ fcnt,
    const int* __restrict__ flags, double* __restrict__ hsmg)
{
  const int f = *flagp;
  int cnt = *fcnt; if (cnt > QCAP) cnt = QCAP;
  const int q = blockIdx.x >> 3;
  if (q >= cnt) return;
  const int chunk = blockIdx.x & 7;
  const int n  = flags[q];
  const int wv = threadIdx.x >> 6;
  const int lane = threadIdx.x & 63;

  float xr[16];
  if (f) {
    const float* xp = (const float*)x + (size_t)n * 1024;
    #pragma unroll
    for (int j = 0; j < 16; ++j) xr[j] = xp[lane + 64 * j];
  } else {
    const u16* xp = (const u16*)x + (size_t)n * 1024;
    #pragma unroll
    for (int j = 0; j < 16; ++j) xr[j] = bf2f(xp[lane + 64 * j]);
  }

  const int h0 = chunk * 64 + wv * 16;
  for (int r = 0; r < 16; ++r) {
    const int h = h0 + r;
    double a0 = 0.0, a1 = 0.0;
    if (f) {
      const float* wr = (const float*)w1 + (size_t)h * 2048;
      #pragma unroll
      for (int j = 0; j < 16; j += 2) {
        a0 += (double)xr[j]     * (double)wr[lane + 64 * j];
        a1 += (double)xr[j + 1] * (double)wr[lane + 64 * (j + 1)];
      }
    } else {
      const u16* wr = (const u16*)w1 + (size_t)h * 2048;
      #pragma unroll
      for (int j = 0; j < 16; j += 2) {
        a0 += (double)xr[j]     * (double)bf2f(wr[lane + 64 * j]);
        a1 += (double)xr[j + 1] * (double)bf2f(wr[lane + 64 * (j + 1)]);
      }
    }
    double a = a0 + a1;
    #pragma unroll
    for (int off = 32; off; off >>= 1) a += __shfl_xor(a, off);
    if (lane == 0) {
      a += b1p64[h];
      hsmg[(size_t)q * 512 + h] =
          0.5 * a * (1.0 + erf(a * 0.70710678118654752440));
    }
  }
}

// ---------------- repair stage 2: logits (lane-parallel) + serial top-8 ----
__global__ __launch_bounds__(256) void k_repair_t(const void* __restrict__ x,
    const void* __restrict__ w1, const void* __restrict__ w2,
    const void* __restrict__ b2, const void* __restrict__ tau,
    const int* __restrict__ flagp, const double* __restrict__ b1p64,
    const int* __restrict__ fcnt, const int* __restrict__ flags,
    const double* __restrict__ hsmg, int* __restrict__ idxb,
    float* __restrict__ wgtb)
{
  __shared__ double hsm[512];
  __shared__ double lg[64];
  const int f = *flagp;
  const int cnt = *fcnt;
  const int t = threadIdx.x;
  const int wv = t >> 6;
  const int lane = t & 63;
  for (int q = blockIdx.x; q < cnt; q += gridDim.x) {
    const int n = flags[q];
    if (q < QCAP) {
      for (int h = t; h < 512; h += 256) hsm[h] = hsmg[(size_t)q * 512 + h];
    } else {
      // fallback: wave per 16-row group, lane-parallel dot
      for (int h = wv; h < 512; h += 4) {
        double a0 = 0.0, a1 = 0.0;
        if (f) {
          const float* xp = (const float*)x + (size_t)n * 1024;
          const float* wr = (const float*)w1 + (size_t)h * 2048;
          for (int j = 0; j < 16; j += 2) {
            a0 += (double)xp[lane + 64 * j]       * (double)wr[lane + 64 * j];
            a1 += (double)xp[lane + 64 * (j + 1)] * (double)wr[lane + 64 * (j + 1)];
          }
        } else {
          const u16* xp = (const u16*)x + (size_t)n * 1024;
          const u16* wr = (const u16*)w1 + (size_t)h * 2048;
          for (int j = 0; j < 16; j += 2) {
            a0 += (double)bf2f(xp[lane + 64 * j]) * (double)bf2f(wr[lane + 64 * j]);
            a1 += (double)bf2f(xp[lane + 64 * (j + 1)]) *
                  (double)bf2f(wr[lane + 64 * (j + 1)]);
          }
        }
        double a = a0 + a1;
        #pragma unroll
        for (int off = 32; off; off >>= 1) a += __shfl_xor(a, off);
        if (lane == 0) {
          a += b1p64[h];
          hsm[h] = 0.5 * a * (1.0 + erf(a * 0.70710678118654752440));
        }
      }
    }
    __syncthreads();
    // logits: wave wv handles outputs s = wv, wv+4, ... (16 each)
    for (int s = wv; s < 64; s += 4) {
      double a0 = 0.0, a1 = 0.0;
      if (f) {
        const float* wr = (const float*)w2 + (size_t)s * 512;
        #pragma unroll
        for (int j = 0; j < 8; j += 2) {
          a0 += hsm[lane + 64 * j]       * (double)wr[lane + 64 * j];
          a1 += hsm[lane + 64 * (j + 1)] * (double)wr[lane + 64 * (j + 1)];
        }
      } else {
        const u16* wr = (const u16*)w2 + (size_t)s * 512;
        #pragma unroll
        for (int j = 0; j < 8; j += 2) {
          a0 += hsm[lane + 64 * j]       * (double)bf2f(wr[lane + 64 * j]);
          a1 += hsm[lane + 64 * (j + 1)] * (double)bf2f(wr[lane + 64 * (j + 1)]);
        }
      }
      double a = a0 + a1;
      #pragma unroll
      for (int off = 32; off; off >>= 1) a += __shfl_xor(a, off);
      if (lane == 0) lg[s] = a + (double)rdval(b2, s, f);
    }
    __syncthreads();
    if (t == 0) {
      double tv = fabs((double)rdval(tau, 0, f)) + 0.1;
      double vals[8]; int ids[8];
      for (int it = 0; it < 8; ++it) {
        double best = -1e300; int bi = 0;
        for (int i = 0; i < 64; ++i)
          if (lg[i] > best) { best = lg[i]; bi = i; }
        vals[it] = best; ids[it] = bi; lg[bi] = -1e300;
      }
      double e[8], z = 0.0;
      for (int k = 0; k < 8; ++k) { e[k] = exp((vals[k] - vals[0]) / tv); z += e[k]; }
      for (int k = 0; k < 8; ++k) {
        idxb[n * 8 + k] = ids[k];
        wgtb[n * 8 + k] = (float)(e[k] / z);
      }
    }
    __syncthreads();
  }
}

// ---------------- dispatch: chunked (b,chunk,slot) partial sums ----------------
// r7 version EXACT (best measured): grid 2048 = 32 windows x 64 slots,
// XCD-aware remap -- each XCD gets 4 complete windows so all 64 slot-blocks
// of a window share one private L2. (r8 scatter and r9 sequential-window
// variants both regressed; reverted.)
__global__ __launch_bounds__(256) void k_dispatch(const void* __restrict__ X,
    const int* __restrict__ flagp, const int* __restrict__ idxb,
    const float* __restrict__ wgtb,
    float* __restrict__ dpart, float* __restrict__ dwsum)
{
  __shared__ int   ltok[512];
  __shared__ float lw[512];
  __shared__ int   lcnt;
  __shared__ float lws;
  const int f32m = *flagp;
  const int g    = blockIdx.x;
  const int xcd  = g & 7;           // HW XCD of this block (round-robin)
  const int ord  = g >> 3;          // 0..255 ordinal within this XCD
  const int win  = xcd * 4 + (ord >> 6);  // 4 windows per XCD, bijective
  const int s    = ord & 63;
  const int b     = win >> 3;
  const int chunk = win & 7;
  const int t     = threadIdx.x;
  if (t == 0) { lcnt = 0; lws = 0.f; }
  __syncthreads();
  const int tok0 = b * 4096 + chunk * 512;
  float mysum = 0.f;
  for (int tok = tok0 + t; tok < tok0 + 512; tok += 256) {
    int hit = -1;
    #pragma unroll
    for (int k = 0; k < 8; ++k)
      if (idxb[(size_t)tok * 8 + k] == s) hit = k;
    if (hit >= 0) {
      float w = wgtb[(size_t)tok * 8 + hit];
      int p = atomicAdd(&lcnt, 1);
      ltok[p] = tok; lw[p] = w;
      mysum += w;
    }
  }
  atomicAdd(&lws, mysum);
  __syncthreads();
  const int cnt = lcnt;
  float a0 = 0.f, a1 = 0.f, a2 = 0.f, a3 = 0.f;
  if (f32m) {
    const float* Xf = (const float*)X;
    for (int e = 0; e < cnt; ++e) {
      int tok = ltok[e]; float w = lw[e];
      const float4 v = *(const float4*)(Xf + (size_t)tok * 1024 + 4 * t);
      a0 += w * v.x; a1 += w * v.y; a2 += w * v.z; a3 += w * v.w;
    }
  } else {
    const u16* Xb = (const u16*)X;
    for (int e = 0; e < cnt; ++e) {
      int tok = ltok[e]; float w = lw[e];
      const ushort4 v = *(const ushort4*)(Xb + (size_t)tok * 1024 + 4 * t);
      a0 += w * bf2f(v.x); a1 += w * bf2f(v.y);
      a2 += w * bf2f(v.z); a3 += w * bf2f(v.w);
    }
  }
  const int bs = b * 64 + s;
  float* pp = dpart + ((size_t)bs * 8 + chunk) * 1024 + 4 * t;
  float4 outv = { a0, a1, a2, a3 };
  *(float4*)pp = outv;
  if (t == 0) dwsum[bs * 8 + chunk] = lws;
}

// reduce 8 chunk partials, normalize, split -> gihi/gilo
__global__ __launch_bounds__(256) void k_dreduce(const float* __restrict__ dpart,
    const float* __restrict__ dwsum, u16* __restrict__ gihi, u16* __restrict__ gilo)
{
  const int bs = blockIdx.x;
  const int t  = threadIdx.x;
  float ws = 0.f;
  #pragma unroll
  for (int c = 0; c < 8; ++c) ws += dwsum[bs * 8 + c];
  const float inv = 1.0f / (ws + 1e-8f);
  float a0 = 0.f, a1 = 0.f, a2 = 0.f, a3 = 0.f;
  const float* pb = dpart + (size_t)bs * 8 * 1024 + 4 * t;
  #pragma unroll
  for (int c = 0; c < 8; ++c) {
    const float4 v = *(const float4*)(pb + c * 1024);
    a0 += v.x; a1 += v.y; a2 += v.z; a3 += v.w;
  }
  const size_t base = (size_t)bs * 1024 + 4 * t;
  splitf(a0 * inv, gihi[base + 0], gilo[base + 0]);
  splitf(a1 * inv, gihi[base + 1], gilo[base + 1]);
  splitf(a2 * inv, gihi[base + 2], gilo[base + 2]);
  splitf(a3 * inv, gihi[base + 3], gilo[base + 3]);
}

// ---------------- GRU elementwise -> S_new split ----------------
__global__ __launch_bounds__(256) void k_gru(const float* __restrict__ gx,
    const float* __restrict__ gh, const float* __restrict__ hsf,
    u16* __restrict__ snhi, u16* __restrict__ snlo)
{
  int gid = blockIdx.x * 256 + threadIdx.x;   // 0..262143
  int r = gid >> 10, d = gid & 1023, s = r & 63;
  const float* gxr = gx + (size_t)r * 3072;
  const float* ghr = gh + (size_t)s * 3072;
  float rr = 1.0f / (1.0f + expf(-(gxr[d] + ghr[d])));
  float zz = 1.0f / (1.0f + expf(-(gxr[1024 + d] + ghr[1024 + d])));
  float nn = tanhf(gxr[2048 + d] + rr * ghr[2048 + d]);
  float hs = hsf[s * 1024 + d];
  float hv = (1.0f - zz) * nn + zz * hs;
  splitf(hv, snhi[gid], snlo[gid]);
}

// ---------------- out[n,:] = sum_k w_k * svo[b,id_k,:]  (svo has bo folded) --
__global__ __launch_bounds__(256) void k_out(const int* __restrict__ idxb,
    const float* __restrict__ wgtb, const float* __restrict__ svo,
    const int* __restrict__ flagp, void* __restrict__ out)
{
  const int f32m = *flagp;
  int n = blockIdx.x * 4 + (threadIdx.x >> 6);
  int lane = threadIdx.x & 63;
  int b = n >> 12;
  const float* svb = svo + (size_t)b * 64 * 1024;
  int id[8]; float w[8];
  #pragma unroll
  for (int k = 0; k < 8; ++k) { id[k] = idxb[n * 8 + k]; w[k] = wgtb[n * 8 + k]; }
  #pragma unroll
  for (int i = 0; i < 16; ++i) {
    int d = i * 64 + lane;
    float a = 0.f;
    #pragma unroll
    for (int k = 0; k < 8; ++k) a += w[k] * svb[(size_t)id[k] * 1024 + d];
    size_t idx = (size_t)n * 1024 + d;
    if (f32m) ((float*)out)[idx] = a;
    else      ((u16*)out)[idx] = f2bf(a);
  }
}

// ---------------- launch ----------------
extern "C" void kernel_launch(void* const* d_in, const int* in_sizes, int n_in,
                              void* d_out, int out_size, void* d_ws, size_t ws_size,
                              hipStream_t stream) {
  if (ws_size < WS_NEED) {  // clean-failure signal
    hipMemsetAsync(d_out, 0, (size_t)out_size * 2, stream);
    return;
  }
  const void* x    = d_in[0];
  const void* sli  = d_in[1];
  const void* slsc = d_in[2];
  const void* w1   = d_in[3];
  const void* b1   = d_in[4];
  const void* w2   = d_in[5];
  const void* b2   = d_in[6];
  const void* wih  = d_in[7];
  const void* whh  = d_in[8];
  const void* bih  = d_in[9];
  const void* bhh  = d_in[10];
  const void* wv   = d_in[11];
  const void* bv   = d_in[12];
  const void* wo   = d_in[13];
  const void* bo   = d_in[14];
  const void* tau  = d_in[15];
  char* ws = (char*)d_ws;

  int*    flag   = (int*)(ws + OFF_FLAG);
  int*    fcnt   = (int*)(ws + OFF_FCNT);
  double* m64    = (double*)(ws + OFF_M);
  double* b1p64  = (double*)(ws + OFF_B1P64);
  float*  b1p32  = (float*)(ws + OFF_B1P32);
  float*  b2f    = (float*)(ws + OFF_B2F);
  float*  bihf   = (float*)(ws + OFF_BIHF);
  float*  bhhf   = (float*)(ws + OFF_BHHF);
  float*  bvf    = (float*)(ws + OFF_BVF);
  float*  bof    = (float*)(ws + OFF_BOF);
  int*    flags  = (int*)(ws + OFF_FLAGS);
  u16*    hshi   = (u16*)(ws + OFF_HSHI);
  u16*    hslo   = (u16*)(ws + OFF_HSLO);
  float*  hsf    = (float*)(ws + OFF_HSF);
  float*  gh     = (float*)(ws + OFF_GH);
  u16*    gihi   = (u16*)(ws + OFF_GIHI);
  u16*    gilo   = (u16*)(ws + OFF_GILO);
  float*  gx     = (float*)(ws + OFF_GX);
  u16*    snhi   = (u16*)(ws + OFF_SNHI);
  u16*    snlo   = (u16*)(ws + OFF_SNLO);
  u16*    svhi   = (u16*)(ws + OFF_SVHI);
  u16*    svlo   = (u16*)(ws + OFF_SVLO);
  float*  svo    = (float*)(ws + OFF_SVO);
  int*    idxb   = (int*)(ws + OFF_IDX);
  float*  wgtb   = (float*)(ws + OFF_WGT);
  float*  logits = (float*)(ws + OFF_LOGITS);
  u16*    w1hi   = (u16*)(ws + OFF_W1HI);
  u16*    w1lo   = (u16*)(ws + OFF_W1LO);
  u16*    w2hi   = (u16*)(ws + OFF_W2HI);
  u16*    w2lo   = (u16*)(ws + OFF_W2LO);
  u16*    wihhi  = (u16*)(ws + OFF_WIHHI);
  u16*    wihlo  = (u16*)(ws + OFF_WIHLO);
  u16*    whhhi  = (u16*)(ws + OFF_WHHHI);
  u16*    whhlo  = (u16*)(ws + OFF_WHHLO);
  u16*    wvhi   = (u16*)(ws + OFF_WVHI);
  u16*    wvlo   = (u16*)(ws + OFF_WVLO);
  u16*    wohi   = (u16*)(ws + OFF_WOHI);
  u16*    wolo   = (u16*)(ws + OFF_WOLO);
  u16*    hhi    = (u16*)(ws + OFF_HHI);
  u16*    hlo    = (u16*)(ws + OFF_HLO);
  float*  dpart  = (float*)(ws + OFF_DPART);
  float*  dwsum  = (float*)(ws + OFF_DWSUM);
  double* hsmg   = (double*)(ws + OFF_HSMG);

  k_sniff<<<1, 64, 0, stream>>>((const u32*)w1, flag);

  k_init<<<64, 256, 0, stream>>>(sli, slsc, flag, m64, fcnt, hshi, hslo, hsf);
  k_b1p<<<2, 256, 0, stream>>>(w1, b1, flag, m64, b1p64, b1p32);

  // all weight hi/lo splits + all f32 bias conversions in ONE launch
  k_cvt_all<<<37025, 256, 0, stream>>>(w1, w2, wih, whh, wv, wo,
                                       b2, bih, bhh, bv, bo, ws, flag);

  // gh = hs @ whh^T + bhh   (64 x 3072)
  gemm_bt<0><<<dim3(1, 24), 512, 0, stream>>>(
      hshi, hslo, whhhi, whhlo, 64, 3072, 1024, 1024, bhhf, gh, nullptr, nullptr,
      flag);

  // h = gelu(x @ w1a^T + b1') -> split  (16384 x 512), x split on the fly
  gemm_router<<<dim3(256, 4), 256, 0, stream>>>(
      x, w1hi, w1lo, NTOK, 512, 1024, 2048, b1p32, hhi, hlo, flag);

  // logits = h @ w2^T + b2   (16384 x 64)
  gemm_bt<0><<<dim3(128, 1), 512, 0, stream>>>(
      hhi, hlo, w2hi, w2lo, NTOK, 64, 512, 512, b2f, logits, nullptr, nullptr,
      flag);

  k_topk<<<4096, 256, 0, stream>>>(logits, tau, flag, idxb, wgtb, fcnt, flags);
  k_repair_h<<<2048, 256, 0, stream>>>(x, w1, flag, b1p64, fcnt, flags, hsmg);
  k_repair_t<<<256, 256, 0, stream>>>(x, w1, w2, b2, tau, flag, b1p64, fcnt,
                                      flags, hsmg, idxb, wgtb);
  k_dispatch<<<2048, 256, 0, stream>>>(x, flag, idxb, wgtb, dpart, dwsum);
  k_dreduce<<<256, 256, 0, stream>>>(dpart, dwsum, gihi, gilo);

  // gx = gi @ wih^T + bih   (256 x 3072)
  gemm_bt<0><<<dim3(2, 24), 512, 0, stream>>>(
      gihi, gilo, wihhi, wihlo, 256, 3072, 1024, 1024, bihf, gx, nullptr, nullptr,
      flag);

  k_gru<<<1024, 256, 0, stream>>>(gx, gh, hsf, snhi, snlo);

  // sv = S_new @ wv^T + bv  (256 x 1024) -> split
  gemm_bt<3><<<dim3(2, 8), 512, 0, stream>>>(
      snhi, snlo, wvhi, wvlo, 256, 1024, 1024, 1024, bvf, nullptr, svhi, svlo,
      flag);

  // svo = sv @ wo^T + bo    (256 x 1024) -> f32
  gemm_bt<0><<<dim3(2, 8), 512, 0, stream>>>(
      svhi, svlo, wohi, wolo, 256, 1024, 1024, 1024, bof, svo, nullptr, nullptr,
      flag);

  k_out<<<4096, 256, 0, stream>>>(idxb, wgtb, svo, flag, d_out);

  (void)in_sizes; (void)n_in; (void)out_size; (void)ws_size;
}

// Round 11
// 656.451 us; speedup vs baseline: 1.0620x; 1.0620x over previous
//
#include <hip/hip_runtime.h>

using u16 = unsigned short;
using u32 = unsigned int;

typedef __attribute__((ext_vector_type(8))) short bf16x8;
typedef __attribute__((ext_vector_type(4))) float f32x4;

#define NTOK 16384

// ---------------- workspace layout (bytes) ----------------
constexpr size_t OFF_FLAG   = 0;         // f32-mode flag
constexpr size_t OFF_FCNT   = 256;       // flagged-token count
constexpr size_t OFF_M      = 512;       // 1024 f64 slot_mean
constexpr size_t OFF_B1P64  = 8704;      // 512 f64
constexpr size_t OFF_B1P32  = 12800;     // 512 f32
constexpr size_t OFF_B2F    = 14848;     // 64 f32
constexpr size_t OFF_BIHF   = 15104;     // 3072 f32
constexpr size_t OFF_BHHF   = 27392;     // 3072 f32
constexpr size_t OFF_BVF    = 39680;     // 1024 f32
constexpr size_t OFF_BOF    = 43776;     // 1024 f32
constexpr size_t OFF_FLAGS  = 47872;     // 16384 int
constexpr size_t OFF_HSHI   = 113408;    // 64*1024 u16
constexpr size_t OFF_HSLO   = 244480;
constexpr size_t OFF_HSF    = 375552;    // 64*1024 f32
constexpr size_t OFF_GH     = 637696;    // 64*3072 f32
constexpr size_t OFF_GIHI   = 1424128;   // 256*1024 u16
constexpr size_t OFF_GILO   = 1948416;
constexpr size_t OFF_GX     = 2472704;   // 256*3072 f32
constexpr size_t OFF_SNHI   = 5618432;   // 256*1024 u16
constexpr size_t OFF_SNLO   = 6142720;
constexpr size_t OFF_SVHI   = 6667008;   // 256*1024 u16
constexpr size_t OFF_SVLO   = 7191296;
constexpr size_t OFF_SVO    = 7715584;   // 256*1024 f32
constexpr size_t OFF_IDX    = 8764160;   // 16384*8 int
constexpr size_t OFF_WGT    = 9288448;   // 16384*8 f32
constexpr size_t OFF_LOGITS = 9812736;   // 16384*64 f32
constexpr size_t OFF_W1HI   = 14007040;  // 512*2048 u16
constexpr size_t OFF_W1LO   = 16104192;
constexpr size_t OFF_W2HI   = 18201344;  // 64*512 u16
constexpr size_t OFF_W2LO   = 18266880;
constexpr size_t OFF_WIHHI  = 18332416;  // 3072*1024 u16
constexpr size_t OFF_WIHLO  = 24623872;
constexpr size_t OFF_WHHHI  = 30915328;
constexpr size_t OFF_WHHLO  = 37206784;
constexpr size_t OFF_WVHI   = 43498240;  // 1024*1024 u16
constexpr size_t OFF_WVLO   = 45595392;
constexpr size_t OFF_WOHI   = 47692544;
constexpr size_t OFF_WOLO   = 49789696;
constexpr size_t OFF_HHI    = 51886848;  // 16384*512 u16
constexpr size_t OFF_HLO    = 68664064;
constexpr size_t OFF_DPART  = 85441280;  // 256*8*1024 f32 dispatch partials
constexpr size_t OFF_DWSUM  = 93829888;  // 256*8 f32 weight-sum partials
constexpr size_t OFF_HSMG   = 93838080;  // 256*512 f64 repair hidden rows
constexpr size_t WS_NEED    = 94886656;  // < 101,169,920 proven available r2

constexpr int QCAP = 256;                // fast-path repair token capacity

// ---------------- helpers ----------------
__device__ __forceinline__ float bf2f(u16 u) {
  union { u32 i; float f; } c; c.i = ((u32)u) << 16; return c.f;
}
__device__ __forceinline__ u16 f2bf(float f) {  // RNE
  u32 x = __float_as_uint(f);
  x += 0x7fffu + ((x >> 16) & 1u);
  return (u16)(x >> 16);
}
__device__ __forceinline__ void splitf(float v, u16& hi, u16& lo) {
  hi = f2bf(v);
  lo = f2bf(v - bf2f(hi));
}
__device__ __forceinline__ float rdval(const void* p, int i, int f32m) {
  return f32m ? ((const float*)p)[i] : bf2f(((const u16*)p)[i]);
}
__device__ __forceinline__ void async16(const u16* g, u16* l) {
  __builtin_amdgcn_global_load_lds((const __attribute__((address_space(1))) void*)g,
                                   (__attribute__((address_space(3))) void*)l, 16, 0, 0);
}

// ---------------- dtype sniffer (f32 vs bf16 input buffers) ----------------
__global__ void k_sniff(const u32* __restrict__ w1w, int* __restrict__ flag) {
  int t = threadIdx.x;
  u32 word = w1w[t * 97];
  int ef = (word >> 7) & 0xFF;                 // exp field of low u16 as bf16
  unsigned long long m = __ballot(ef >= 128);  // |v|>=2 impossible for bf16 wts
  if (t == 0) flag[0] = (__popcll(m) >= 8) ? 1 : 0;
}

// ---------------- batched conversions (one launch) --------------
__global__ __launch_bounds__(256) void k_cvt_all(
    const void* __restrict__ w1, const void* __restrict__ w2,
    const void* __restrict__ wih, const void* __restrict__ whh,
    const void* __restrict__ wv, const void* __restrict__ wo,
    const void* __restrict__ b2, const void* __restrict__ bih,
    const void* __restrict__ bhh, const void* __restrict__ bv,
    const void* __restrict__ bo, char* __restrict__ ws,
    const int* __restrict__ flagp)
{
  const int f = *flagp;
  const long long gid = (long long)blockIdx.x * 256 + threadIdx.x;
  const long long C0 = 1048576, C1 = C0 + 32768, C2 = C1 + 3145728,
                  C3 = C2 + 3145728, C4 = C3 + 1048576, C5 = C4 + 1048576;
  if (gid < C5) {
    const void* src; size_t oh, ol; int i;
    if (gid < C0)      { src = w1;  oh = OFF_W1HI;  ol = OFF_W1LO;  i = (int)gid; }
    else if (gid < C1) { src = w2;  oh = OFF_W2HI;  ol = OFF_W2LO;  i = (int)(gid - C0); }
    else if (gid < C2) { src = wih; oh = OFF_WIHHI; ol = OFF_WIHLO; i = (int)(gid - C1); }
    else if (gid < C3) { src = whh; oh = OFF_WHHHI; ol = OFF_WHHLO; i = (int)(gid - C2); }
    else if (gid < C4) { src = wv;  oh = OFF_WVHI;  ol = OFF_WVLO;  i = (int)(gid - C3); }
    else               { src = wo;  oh = OFF_WOHI;  ol = OFF_WOLO;  i = (int)(gid - C4); }
    float v = rdval(src, i, f);
    u16 hi, lo; splitf(v, hi, lo);
    ((u16*)(ws + oh))[i] = hi;
    ((u16*)(ws + ol))[i] = lo;
    return;
  }
  int r = (int)(gid - C5);
  if (r >= 8256) return;
  const void* src; size_t od; int i;
  if (r < 64)        { src = b2;  od = OFF_B2F;  i = r; }
  else if (r < 3136) { src = bih; od = OFF_BIHF; i = r - 64; }
  else if (r < 6208) { src = bhh; od = OFF_BHHF; i = r - 3136; }
  else if (r < 7232) { src = bv;  od = OFF_BVF;  i = r - 6208; }
  else               { src = bo;  od = OFF_BOF;  i = r - 7232; }
  ((float*)(ws + od))[i] = rdval(src, i, f);
}

// ---------------- bt-GEMM: C[M,N] = A[M,K] @ B[N,K]^T ----------------
// r4 structure (proven). 512 threads = 2 within-block K-groups x 4 waves;
// 3 split passes flat loop, double-buffered LDS, one vmcnt(0)+barrier per
// step. Group1 partial folded into group0 via 128x64 LDS f32 tile.
// MODE 0: f32 out. MODE 3: split-bf16 out.
template<int MODE>
__global__ __launch_bounds__(512, 2) void gemm_bt(
    const u16* __restrict__ Ahi, const u16* __restrict__ Alo,
    const u16* __restrict__ Bhi, const u16* __restrict__ Blo,
    int M, int N, int K, int ldb,
    const float* __restrict__ biasF, float* __restrict__ outF,
    u16* __restrict__ outHi, u16* __restrict__ outLo)
{
  __shared__ alignas(16) u16 smem[2 * 2 * 8192];  // [grp][buf][At 4096|Bt 4096]
  const int t    = threadIdx.x;
  const int grp  = t >> 8;
  const int tl   = t & 255;
  const int wvid = tl >> 6;
  const int lane = t & 63;
  const int quad = lane >> 4;
  const int l16  = lane & 15;
  const int row0 = blockIdx.x * 128;
  const int col0 = blockIdx.y * 128;
  const int wr   = (wvid >> 1) * 64;
  const int wc   = (wvid & 1) * 64;

  const int ra  = tl >> 2;
  const int kqe = (tl & 3) * 8;
  int r_a0 = row0 + ra;      if (r_a0 > M - 1) r_a0 = M - 1;
  int r_a1 = row0 + ra + 64; if (r_a1 > M - 1) r_a1 = M - 1;
  int r_b0 = col0 + ra;      if (r_b0 > N - 1) r_b0 = N - 1;
  int r_b1 = col0 + ra + 64; if (r_b1 > N - 1) r_b1 = N - 1;
  const size_t aoff0 = (size_t)r_a0 * K + kqe;
  const size_t aoff1 = (size_t)r_a1 * K + kqe;
  const size_t boff0 = (size_t)r_b0 * ldb + kqe;
  const size_t boff1 = (size_t)r_b1 * ldb + kqe;

  const int KH  = K >> 1;             // per-group K range
  const int NIT = 3 * (KH >> 5);      // 3 passes x KH/32 steps
  int sp = 0, sk = grp * KH;          // stage cursors (pass, k-offset)
  const int skend = grp * KH + KH;

  u16* const base = smem + grp * 16384;
  auto stage = [&](int buf) {
    const u16* Ap = (sp == 1) ? Alo : Ahi;
    const u16* Bp = (sp == 2) ? Blo : Bhi;
    u16* At = base + buf * 8192;
    u16* Bt = At + 4096;
    async16(Ap + aoff0 + sk, &At[(wvid * 64) * 8]);
    async16(Ap + aoff1 + sk, &At[(wvid * 64 + 256) * 8]);
    async16(Bp + boff0 + sk, &Bt[(wvid * 64) * 8]);
    async16(Bp + boff1 + sk, &Bt[(wvid * 64 + 256) * 8]);
    sk += 32;
    if (sk == skend) { sk = grp * KH; ++sp; }
  };

  f32x4 acc[4][4] = {};
  stage(0);
  asm volatile("s_waitcnt vmcnt(0)" ::: "memory");
  __syncthreads();
  int cur = 0;
  for (int it = 0; it < NIT; ++it) {
    if (it + 1 < NIT) stage(cur ^ 1);   // prefetch next K-step into other buf
    const u16* At = base + cur * 8192;
    const u16* Bt = At + 4096;
    bf16x8 af[4], bfr[4];
    #pragma unroll
    for (int mt = 0; mt < 4; ++mt)
      af[mt] = *(const bf16x8*)&At[(wr + mt * 16 + l16) * 32 + quad * 8];
    #pragma unroll
    for (int nt = 0; nt < 4; ++nt)
      bfr[nt] = *(const bf16x8*)&Bt[(wc + nt * 16 + l16) * 32 + quad * 8];
    #pragma unroll
    for (int mt = 0; mt < 4; ++mt)
      #pragma unroll
      for (int nt = 0; nt < 4; ++nt)
        acc[mt][nt] = __builtin_amdgcn_mfma_f32_16x16x32_bf16(
            af[mt], bfr[nt], acc[mt][nt], 0, 0, 0);
    asm volatile("s_waitcnt vmcnt(0)" ::: "memory");
    __syncthreads();
    cur ^= 1;
  }

  // fold: group1 partial -> group0, two wc-halves via 128x64 f32 LDS tile
  float* red = (float*)smem;            // 32 KB, staging dead after loop
  #pragma unroll 1
  for (int half = 0; half < 2; ++half) {
    if (grp == 1 && (wvid & 1) == half) {
      #pragma unroll
      for (int mt = 0; mt < 4; ++mt)
        #pragma unroll
        for (int nt = 0; nt < 4; ++nt)
          #pragma unroll
          for (int r2 = 0; r2 < 4; ++r2)
            red[(wr + mt * 16 + quad * 4 + r2) * 64 + nt * 16 + l16] =
                acc[mt][nt][r2];
    }
    __syncthreads();
    if (grp == 0 && (wvid & 1) == half) {
      #pragma unroll
      for (int mt = 0; mt < 4; ++mt)
        #pragma unroll
        for (int nt = 0; nt < 4; ++nt)
          #pragma unroll
          for (int r2 = 0; r2 < 4; ++r2)
            acc[mt][nt][r2] +=
                red[(wr + mt * 16 + quad * 4 + r2) * 64 + nt * 16 + l16];
    }
    __syncthreads();
  }
  if (grp != 0) return;

  #pragma unroll
  for (int mt = 0; mt < 4; ++mt) {
    #pragma unroll
    for (int nt = 0; nt < 4; ++nt) {
      const int col = col0 + wc + nt * 16 + l16;
      if (col >= N) continue;
      #pragma unroll
      for (int r2 = 0; r2 < 4; ++r2) {
        const int row = row0 + wr + mt * 16 + quad * 4 + r2;
        if (row >= M) continue;
        float v = acc[mt][nt][r2] + biasF[col];
        size_t idx = (size_t)row * N + col;
        if constexpr (MODE == 0) {
          outF[idx] = v;
        } else {
          u16 hi, lo; splitf(v, hi, lo);
          outHi[idx] = hi; outLo[idx] = lo;
        }
      }
    }
  }
}

// ---------------- router GEMM: h = gelu(x @ w1a^T + b1'), x split on the fly
// r7 structure (proven best, 103us): scalar splitf, single-buffer B,
// vmcnt(0)+__syncthreads, T14 x-register-prefetch one k-step ahead.
__global__ __launch_bounds__(256, 4) void gemm_router(
    const void* __restrict__ X,
    const u16* __restrict__ Bhi, const u16* __restrict__ Blo,
    int M, int N, int K, int ldb, const float* __restrict__ biasF,
    u16* __restrict__ outHi, u16* __restrict__ outLo,
    const int* __restrict__ flagp)
{
  __shared__ alignas(16) u16 Athi[64 * 32];
  __shared__ alignas(16) u16 Atlo[64 * 32];
  __shared__ alignas(16) u16 Bthi[128 * 32];
  __shared__ alignas(16) u16 Btlo[128 * 32];
  const int f32m = *flagp;
  const int t    = threadIdx.x;
  const int wvid = t >> 6;
  const int lane = t & 63;
  const int quad = lane >> 4;
  const int l16  = lane & 15;
  const int row0 = blockIdx.x * 64;
  const int col0 = blockIdx.y * 128;
  const int wr   = (wvid >> 1) * 32;     // wave covers 32 rows x 64 cols
  const int wc   = (wvid & 1) * 64;

  const int ra  = t >> 2;
  const int kqe = (t & 3) * 8;
  int r_b0 = col0 + ra;      if (r_b0 > N - 1) r_b0 = N - 1;
  int r_b1 = col0 + ra + 64; if (r_b1 > N - 1) r_b1 = N - 1;
  const u16* gBhi0 = Bhi + (size_t)r_b0 * ldb + kqe;
  const u16* gBhi1 = Bhi + (size_t)r_b1 * ldb + kqe;
  const u16* gBlo0 = Blo + (size_t)r_b0 * ldb + kqe;
  const u16* gBlo1 = Blo + (size_t)r_b1 * ldb + kqe;

  // fixed per-thread A-stage source/dest (row,kq constant across k-steps)
  const float* xsf[2];
  const u16*   xsb[2];
  u16 *adh[2], *adl[2];
  #pragma unroll
  for (int i = 0; i < 2; ++i) {
    int j = t + 256 * i;
    int row = j >> 3, kq = (j & 7) * 4;
    int grow = row0 + row; if (grow > M - 1) grow = M - 1;
    xsf[i] = (const float*)X + (size_t)grow * K + kq;
    xsb[i] = (const u16*)X + (size_t)grow * K + kq;
    adh[i] = &Athi[row * 32 + kq];
    adl[i] = &Atlo[row * 32 + kq];
  }

  f32x4 acc[2][4] = {};
  float4  xv0, xv1;   // prefetched x (f32 mode)
  ushort4 xb0, xb1;   // prefetched x (bf16 mode)
  if (f32m) { xv0 = *(const float4*)xsf[0];  xv1 = *(const float4*)xsf[1]; }
  else      { xb0 = *(const ushort4*)xsb[0]; xb1 = *(const ushort4*)xsb[1]; }

  for (int k0 = 0; k0 < K; k0 += 32) {
    async16(gBhi0 + k0, &Bthi[(wvid * 64) * 8]);
    async16(gBhi1 + k0, &Bthi[(wvid * 64 + 256) * 8]);
    async16(gBlo0 + k0, &Btlo[(wvid * 64) * 8]);
    async16(gBlo1 + k0, &Btlo[(wvid * 64 + 256) * 8]);
    // ---- stage prefetched x(k0) regs -> LDS (no load latency on path) ----
    {
      ushort4 hi4, lo4;
      if (f32m) {
        splitf(xv0.x, hi4.x, lo4.x);
        splitf(xv0.y, hi4.y, lo4.y);
        splitf(xv0.z, hi4.z, lo4.z);
        splitf(xv0.w, hi4.w, lo4.w);
      } else {
        hi4 = xb0; lo4.x = lo4.y = lo4.z = lo4.w = 0;
      }
      *(ushort4*)adh[0] = hi4;
      *(ushort4*)adl[0] = lo4;
      if (f32m) {
        splitf(xv1.x, hi4.x, lo4.x);
        splitf(xv1.y, hi4.y, lo4.y);
        splitf(xv1.z, hi4.z, lo4.z);
        splitf(xv1.w, hi4.w, lo4.w);
      } else {
        hi4 = xb1; lo4.x = lo4.y = lo4.z = lo4.w = 0;
      }
      *(ushort4*)adh[1] = hi4;
      *(ushort4*)adl[1] = lo4;
    }
    // ---- issue x(k0+32) prefetch; flies during B-drain + barriers ----
    if (k0 + 32 < K) {
      if (f32m) {
        xv0 = *(const float4*)(xsf[0] + k0 + 32);
        xv1 = *(const float4*)(xsf[1] + k0 + 32);
      } else {
        xb0 = *(const ushort4*)(xsb[0] + k0 + 32);
        xb1 = *(const ushort4*)(xsb[1] + k0 + 32);
      }
    }
    asm volatile("s_waitcnt vmcnt(0)" ::: "memory");
    __syncthreads();
    bf16x8 ah[2], al[2], bh[4], bl[4];
    #pragma unroll
    for (int mt = 0; mt < 2; ++mt) {
      ah[mt] = *(const bf16x8*)&Athi[(wr + mt * 16 + l16) * 32 + quad * 8];
      al[mt] = *(const bf16x8*)&Atlo[(wr + mt * 16 + l16) * 32 + quad * 8];
    }
    #pragma unroll
    for (int nt = 0; nt < 4; ++nt) {
      bh[nt] = *(const bf16x8*)&Bthi[(wc + nt * 16 + l16) * 32 + quad * 8];
      bl[nt] = *(const bf16x8*)&Btlo[(wc + nt * 16 + l16) * 32 + quad * 8];
    }
    #pragma unroll
    for (int mt = 0; mt < 2; ++mt)
      #pragma unroll
      for (int nt = 0; nt < 4; ++nt) {
        acc[mt][nt] = __builtin_amdgcn_mfma_f32_16x16x32_bf16(
            ah[mt], bh[nt], acc[mt][nt], 0, 0, 0);
        acc[mt][nt] = __builtin_amdgcn_mfma_f32_16x16x32_bf16(
            al[mt], bh[nt], acc[mt][nt], 0, 0, 0);
        acc[mt][nt] = __builtin_amdgcn_mfma_f32_16x16x32_bf16(
            ah[mt], bl[nt], acc[mt][nt], 0, 0, 0);
      }
    __syncthreads();
  }

  #pragma unroll
  for (int mt = 0; mt < 2; ++mt) {
    #pragma unroll
    for (int nt = 0; nt < 4; ++nt) {
      const int col = col0 + wc + nt * 16 + l16;
      if (col >= N) continue;
      #pragma unroll
      for (int r2 = 0; r2 < 4; ++r2) {
        const int row = row0 + wr + mt * 16 + quad * 4 + r2;
        if (row >= M) continue;
        float v = acc[mt][nt][r2] + biasF[col];
        v = 0.5f * v * (1.0f + erff(v * 0.70710678118654752f));
        u16 hi, lo; splitf(v, hi, lo);
        size_t idx = (size_t)row * N + col;
        outHi[idx] = hi; outLo[idx] = lo;
      }
    }
  }
}

// ---------------- init: fcnt=0, slot_mean f64, hs split + f32 ----------------
__global__ __launch_bounds__(256) void k_init(const void* __restrict__ sli,
    const void* __restrict__ slsc, const int* __restrict__ flagp,
    double* __restrict__ m64, int* __restrict__ fcnt,
    u16* __restrict__ hshi, u16* __restrict__ hslo, float* __restrict__ hsf)
{
  int f = *flagp;
  int gid = blockIdx.x * 256 + threadIdx.x;
  if (gid == 0) fcnt[0] = 0;
  if (gid < 1024) {
    double s = 0.0;
    for (int j = 0; j < 64; ++j)
      s += (double)rdval(sli, j * 1024 + gid, f) * (double)rdval(slsc, j, f);
    m64[gid] = s * (1.0 / 64.0);
  }
  for (int i = gid; i < 64 * 1024; i += 16384) {
    int s = i >> 10;
    float v = rdval(sli, i, f) * rdval(slsc, s, f);
    splitf(v, hshi[i], hslo[i]);
    hsf[i] = v;
  }
}

// b1' = b1 + w1[:,1024:2048] @ slot_mean   (f64)
__global__ __launch_bounds__(256) void k_b1p(const void* __restrict__ w1,
    const void* __restrict__ b1, const int* __restrict__ flagp,
    const double* __restrict__ m64, double* __restrict__ b1p64,
    float* __restrict__ b1p32)
{
  int f = *flagp;
  int h = blockIdx.x * 256 + threadIdx.x;
  if (h >= 512) return;
  double a = (double)rdval(b1, h, f);
  if (f) {
    const float* wr = (const float*)w1 + (size_t)h * 2048 + 1024;
    for (int d = 0; d < 1024; ++d) a += (double)wr[d] * m64[d];
  } else {
    const u16* wr = (const u16*)w1 + (size_t)h * 2048 + 1024;
    for (int d = 0; d < 1024; ++d) a += (double)bf2f(wr[d]) * m64[d];
  }
  b1p64[h] = a;
  b1p32[h] = (float)a;
}

// ---------------- top-k per token (wave = token) ----------------
__global__ __launch_bounds__(256) void k_topk(const float* __restrict__ logits,
    const void* __restrict__ tau, const int* __restrict__ flagp,
    int* __restrict__ idxb, float* __restrict__ wgtb,
    int* __restrict__ fcnt, int* __restrict__ flags)
{
  const int f32m = *flagp;
  const int n    = blockIdx.x * 4 + (threadIdx.x >> 6);
  const int lane = threadIdx.x & 63;
  float cur = logits[(size_t)n * 64 + lane];
  float tv[8]; int ti[8]; float v9 = 0.f;
  #pragma unroll
  for (int it = 0; it < 9; ++it) {
    float v = cur; int i = lane;
    #pragma unroll
    for (int off = 32; off; off >>= 1) {   // xor-butterfly argmax, tie -> min idx
      float ov = __shfl_xor(v, off);
      int   oi = __shfl_xor(i, off);
      if (ov > v || (ov == v && oi < i)) { v = ov; i = oi; }
    }
    if (it < 8) { tv[it] = v; ti[it] = i; if (lane == i) cur = -__builtin_inff(); }
    else v9 = v;
  }
  float itau = 1.0f / (fabsf(rdval(tau, 0, f32m)) + 0.1f);
  float e[8], z = 0.f;
  #pragma unroll
  for (int k = 0; k < 8; ++k) { e[k] = expf((tv[k] - tv[0]) * itau); z += e[k]; }
  if (lane == 0) {
    float theta = f32m ? 2e-4f : 1e-4f;   // 18+ sigma above logit noise
    if (tv[7] - v9 < theta) { int p = atomicAdd(fcnt, 1); flags[p] = n; }
    float rz = 1.0f / z;
    #pragma unroll
    for (int k = 0; k < 8; ++k) {
      idxb[n * 8 + k] = ti[k];
      wgtb[n * 8 + k] = e[k] * rz;
    }
  }
}

// ---------------- f64 re-route of flagged tokens, stage 1 ----------------
__global__ __launch_bounds__(256) void k_repair_h(const void* __restrict__ x,
    const void* __restrict__ w1, const int* __restrict__ flagp,
    const double* __restrict__ b1p64, const int* __restrict__ fcnt,
    const int* __restrict__ flags, double* __restrict__ hsmg)
{
  const int f = *flagp;
  int cnt = *fcnt; if (cnt > QCAP) cnt = QCAP;
  const int q = blockIdx.x >> 3;
  if (q >= cnt) return;
  const int chunk = blockIdx.x & 7;
  const int n  = flags[q];
  const int wv = threadIdx.x >> 6;
  const int lane = threadIdx.x & 63;

  float xr[16];
  if (f) {
    const float* xp = (const float*)x + (size_t)n * 1024;
    #pragma unroll
    for (int j = 0; j < 16; ++j) xr[j] = xp[lane + 64 * j];
  } else {
    const u16* xp = (const u16*)x + (size_t)n * 1024;
    #pragma unroll
    for (int j = 0; j < 16; ++j) xr[j] = bf2f(xp[lane + 64 * j]);
  }

  const int h0 = chunk * 64 + wv * 16;
  for (int r = 0; r < 16; ++r) {
    const int h = h0 + r;
    double a0 = 0.0, a1 = 0.0;
    if (f) {
      const float* wr = (const float*)w1 + (size_t)h * 2048;
      #pragma unroll
      for (int j = 0; j < 16; j += 2) {
        a0 += (double)xr[j]     * (double)wr[lane + 64 * j];
        a1 += (double)xr[j + 1] * (double)wr[lane + 64 * (j + 1)];
      }
    } else {
      const u16* wr = (const u16*)w1 + (size_t)h * 2048;
      #pragma unroll
      for (int j = 0; j < 16; j += 2) {
        a0 += (double)xr[j]     * (double)bf2f(wr[lane + 64 * j]);
        a1 += (double)xr[j + 1] * (double)bf2f(wr[lane + 64 * (j + 1)]);
      }
    }
    double a = a0 + a1;
    #pragma unroll
    for (int off = 32; off; off >>= 1) a += __shfl_xor(a, off);
    if (lane == 0) {
      a += b1p64[h];
      hsmg[(size_t)q * 512 + h] =
          0.5 * a * (1.0 + erf(a * 0.70710678118654752440));
    }
  }
}

// ---------------- repair stage 2: logits (lane-parallel) + serial top-8 ----
__global__ __launch_bounds__(256) void k_repair_t(const void* __restrict__ x,
    const void* __restrict__ w1, const void* __restrict__ w2,
    const void* __restrict__ b2, const void* __restrict__ tau,
    const int* __restrict__ flagp, const double* __restrict__ b1p64,
    const int* __restrict__ fcnt, const int* __restrict__ flags,
    const double* __restrict__ hsmg, int* __restrict__ idxb,
    float* __restrict__ wgtb)
{
  __shared__ double hsm[512];
  __shared__ double lg[64];
  const int f = *flagp;
  const int cnt = *fcnt;
  const int t = threadIdx.x;
  const int wv = t >> 6;
  const int lane = t & 63;
  for (int q = blockIdx.x; q < cnt; q += gridDim.x) {
    const int n = flags[q];
    if (q < QCAP) {
      for (int h = t; h < 512; h += 256) hsm[h] = hsmg[(size_t)q * 512 + h];
    } else {
      // fallback: wave per 16-row group, lane-parallel dot
      for (int h = wv; h < 512; h += 4) {
        double a0 = 0.0, a1 = 0.0;
        if (f) {
          const float* xp = (const float*)x + (size_t)n * 1024;
          const float* wr = (const float*)w1 + (size_t)h * 2048;
          for (int j = 0; j < 16; j += 2) {
            a0 += (double)xp[lane + 64 * j]       * (double)wr[lane + 64 * j];
            a1 += (double)xp[lane + 64 * (j + 1)] * (double)wr[lane + 64 * (j + 1)];
          }
        } else {
          const u16* xp = (const u16*)x + (size_t)n * 1024;
          const u16* wr = (const u16*)w1 + (size_t)h * 2048;
          for (int j = 0; j < 16; j += 2) {
            a0 += (double)bf2f(xp[lane + 64 * j]) * (double)bf2f(wr[lane + 64 * j]);
            a1 += (double)bf2f(xp[lane + 64 * (j + 1)]) *
                  (double)bf2f(wr[lane + 64 * (j + 1)]);
          }
        }
        double a = a0 + a1;
        #pragma unroll
        for (int off = 32; off; off >>= 1) a += __shfl_xor(a, off);
        if (lane == 0) {
          a += b1p64[h];
          hsm[h] = 0.5 * a * (1.0 + erf(a * 0.70710678118654752440));
        }
      }
    }
    __syncthreads();
    // logits: wave wv handles outputs s = wv, wv+4, ... (16 each)
    for (int s = wv; s < 64; s += 4) {
      double a0 = 0.0, a1 = 0.0;
      if (f) {
        const float* wr = (const float*)w2 + (size_t)s * 512;
        #pragma unroll
        for (int j = 0; j < 8; j += 2) {
          a0 += hsm[lane + 64 * j]       * (double)wr[lane + 64 * j];
          a1 += hsm[lane + 64 * (j + 1)] * (double)wr[lane + 64 * (j + 1)];
        }
      } else {
        const u16* wr = (const u16*)w2 + (size_t)s * 512;
        #pragma unroll
        for (int j = 0; j < 8; j += 2) {
          a0 += hsm[lane + 64 * j]       * (double)bf2f(wr[lane + 64 * j]);
          a1 += hsm[lane + 64 * (j + 1)] * (double)bf2f(wr[lane + 64 * (j + 1)]);
        }
      }
      double a = a0 + a1;
      #pragma unroll
      for (int off = 32; off; off >>= 1) a += __shfl_xor(a, off);
      if (lane == 0) lg[s] = a + (double)rdval(b2, s, f);
    }
    __syncthreads();
    if (t == 0) {
      double tv = fabs((double)rdval(tau, 0, f)) + 0.1;
      double vals[8]; int ids[8];
      for (int it = 0; it < 8; ++it) {
        double best = -1e300; int bi = 0;
        for (int i = 0; i < 64; ++i)
          if (lg[i] > best) { best = lg[i]; bi = i; }
        vals[it] = best; ids[it] = bi; lg[bi] = -1e300;
      }
      double e[8], z = 0.0;
      for (int k = 0; k < 8; ++k) { e[k] = exp((vals[k] - vals[0]) / tv); z += e[k]; }
      for (int k = 0; k < 8; ++k) {
        idxb[n * 8 + k] = ids[k];
        wgtb[n * 8 + k] = (float)(e[k] / z);
      }
    }
    __syncthreads();
  }
}

// ---------------- dispatch: chunked (b,chunk,slot) partial sums ----------------
// grid 2048 = 32 windows x 64 slots, XCD-aware remap (4 windows per XCD).
__global__ __launch_bounds__(256) void k_dispatch(const void* __restrict__ X,
    const int* __restrict__ flagp, const int* __restrict__ idxb,
    const float* __restrict__ wgtb,
    float* __restrict__ dpart, float* __restrict__ dwsum)
{
  __shared__ int   ltok[512];
  __shared__ float lw[512];
  __shared__ int   lcnt;
  __shared__ float lws;
  const int f32m = *flagp;
  const int g    = blockIdx.x;
  const int xcd  = g & 7;           // HW XCD of this block (round-robin)
  const int ord  = g >> 3;          // 0..255 ordinal within this XCD
  const int win  = xcd * 4 + (ord >> 6);  // 4 windows per XCD, bijective
  const int s    = ord & 63;
  const int b     = win >> 3;
  const int chunk = win & 7;
  const int t     = threadIdx.x;
  if (t == 0) { lcnt = 0; lws = 0.f; }
  __syncthreads();
  const int tok0 = b * 4096 + chunk * 512;
  float mysum = 0.f;
  for (int tok = tok0 + t; tok < tok0 + 512; tok += 256) {
    int hit = -1;
    #pragma unroll
    for (int k = 0; k < 8; ++k)
      if (idxb[(size_t)tok * 8 + k] == s) hit = k;
    if (hit >= 0) {
      float w = wgtb[(size_t)tok * 8 + hit];
      int p = atomicAdd(&lcnt, 1);
      ltok[p] = tok; lw[p] = w;
      mysum += w;
    }
  }
  atomicAdd(&lws, mysum);
  __syncthreads();
  const int cnt = lcnt;
  float a0 = 0.f, a1 = 0.f, a2 = 0.f, a3 = 0.f;
  if (f32m) {
    const float* Xf = (const float*)X;
    for (int e = 0; e < cnt; ++e) {
      int tok = ltok[e]; float w = lw[e];
      const float4 v = *(const float4*)(Xf + (size_t)tok * 1024 + 4 * t);
      a0 += w * v.x; a1 += w * v.y; a2 += w * v.z; a3 += w * v.w;
    }
  } else {
    const u16* Xb = (const u16*)X;
    for (int e = 0; e < cnt; ++e) {
      int tok = ltok[e]; float w = lw[e];
      const ushort4 v = *(const ushort4*)(Xb + (size_t)tok * 1024 + 4 * t);
      a0 += w * bf2f(v.x); a1 += w * bf2f(v.y);
      a2 += w * bf2f(v.z); a3 += w * bf2f(v.w);
    }
  }
  const int bs = b * 64 + s;
  float* pp = dpart + ((size_t)bs * 8 + chunk) * 1024 + 4 * t;
  float4 outv = { a0, a1, a2, a3 };
  *(float4*)pp = outv;
  if (t == 0) dwsum[bs * 8 + chunk] = lws;
}

// reduce 8 chunk partials, normalize, split -> gihi/gilo
__global__ __launch_bounds__(256) void k_dreduce(const float* __restrict__ dpart,
    const float* __restrict__ dwsum, u16* __restrict__ gihi, u16* __restrict__ gilo)
{
  const int bs = blockIdx.x;
  const int t  = threadIdx.x;
  float ws = 0.f;
  #pragma unroll
  for (int c = 0; c < 8; ++c) ws += dwsum[bs * 8 + c];
  const float inv = 1.0f / (ws + 1e-8f);
  float a0 = 0.f, a1 = 0.f, a2 = 0.f, a3 = 0.f;
  const float* pb = dpart + (size_t)bs * 8 * 1024 + 4 * t;
  #pragma unroll
  for (int c = 0; c < 8; ++c) {
    const float4 v = *(const float4*)(pb + c * 1024);
    a0 += v.x; a1 += v.y; a2 += v.z; a3 += v.w;
  }
  const size_t base = (size_t)bs * 1024 + 4 * t;
  splitf(a0 * inv, gihi[base + 0], gilo[base + 0]);
  splitf(a1 * inv, gihi[base + 1], gilo[base + 1]);
  splitf(a2 * inv, gihi[base + 2], gilo[base + 2]);
  splitf(a3 * inv, gihi[base + 3], gilo[base + 3]);
}

// ---------------- GRU elementwise -> S_new split ----------------
__global__ __launch_bounds__(256) void k_gru(const float* __restrict__ gx,
    const float* __restrict__ gh, const float* __restrict__ hsf,
    u16* __restrict__ snhi, u16* __restrict__ snlo)
{
  int gid = blockIdx.x * 256 + threadIdx.x;   // 0..262143
  int r = gid >> 10, d = gid & 1023, s = r & 63;
  const float* gxr = gx + (size_t)r * 3072;
  const float* ghr = gh + (size_t)s * 3072;
  float rr = 1.0f / (1.0f + expf(-(gxr[d] + ghr[d])));
  float zz = 1.0f / (1.0f + expf(-(gxr[1024 + d] + ghr[1024 + d])));
  float nn = tanhf(gxr[2048 + d] + rr * ghr[2048 + d]);
  float hs = hsf[s * 1024 + d];
  float hv = (1.0f - zz) * nn + zz * hs;
  splitf(hv, snhi[gid], snlo[gid]);
}

// ---------------- out[n,:] = sum_k w_k * svo[b,id_k,:]  (svo has bo folded) --
__global__ __launch_bounds__(256) void k_out(const int* __restrict__ idxb,
    const float* __restrict__ wgtb, const float* __restrict__ svo,
    const int* __restrict__ flagp, void* __restrict__ out)
{
  const int f32m = *flagp;
  int n = blockIdx.x * 4 + (threadIdx.x >> 6);
  int lane = threadIdx.x & 63;
  int b = n >> 12;
  const float* svb = svo + (size_t)b * 64 * 1024;
  int id[8]; float w[8];
  #pragma unroll
  for (int k = 0; k < 8; ++k) { id[k] = idxb[n * 8 + k]; w[k] = wgtb[n * 8 + k]; }
  #pragma unroll
  for (int i = 0; i < 16; ++i) {
    int d = i * 64 + lane;
    float a = 0.f;
    #pragma unroll
    for (int k = 0; k < 8; ++k) a += w[k] * svb[(size_t)id[k] * 1024 + d];
    size_t idx = (size_t)n * 1024 + d;
    if (f32m) ((float*)out)[idx] = a;
    else      ((u16*)out)[idx] = f2bf(a);
  }
}

// ---------------- launch ----------------
extern "C" void kernel_launch(void* const* d_in, const int* in_sizes, int n_in,
                              void* d_out, int out_size, void* d_ws, size_t ws_size,
                              hipStream_t stream) {
  if (ws_size < WS_NEED) {  // clean-failure signal
    hipMemsetAsync(d_out, 0, (size_t)out_size * 2, stream);
    return;
  }
  const void* x    = d_in[0];
  const void* sli  = d_in[1];
  const void* slsc = d_in[2];
  const void* w1   = d_in[3];
  const void* b1   = d_in[4];
  const void* w2   = d_in[5];
  const void* b2   = d_in[6];
  const void* wih  = d_in[7];
  const void* whh  = d_in[8];
  const void* bih  = d_in[9];
  const void* bhh  = d_in[10];
  const void* wv   = d_in[11];
  const void* bv   = d_in[12];
  const void* wo   = d_in[13];
  const void* bo   = d_in[14];
  const void* tau  = d_in[15];
  char* ws = (char*)d_ws;

  int*    flag   = (int*)(ws + OFF_FLAG);
  int*    fcnt   = (int*)(ws + OFF_FCNT);
  double* m64    = (double*)(ws + OFF_M);
  double* b1p64  = (double*)(ws + OFF_B1P64);
  float*  b1p32  = (float*)(ws + OFF_B1P32);
  float*  b2f    = (float*)(ws + OFF_B2F);
  float*  bihf   = (float*)(ws + OFF_BIHF);
  float*  bhhf   = (float*)(ws + OFF_BHHF);
  float*  bvf    = (float*)(ws + OFF_BVF);
  float*  bof    = (float*)(ws + OFF_BOF);
  int*    flags  = (int*)(ws + OFF_FLAGS);
  u16*    hshi   = (u16*)(ws + OFF_HSHI);
  u16*    hslo   = (u16*)(ws + OFF_HSLO);
  float*  hsf    = (float*)(ws + OFF_HSF);
  float*  gh     = (float*)(ws + OFF_GH);
  u16*    gihi   = (u16*)(ws + OFF_GIHI);
  u16*    gilo   = (u16*)(ws + OFF_GILO);
  float*  gx     = (float*)(ws + OFF_GX);
  u16*    snhi   = (u16*)(ws + OFF_SNHI);
  u16*    snlo   = (u16*)(ws + OFF_SNLO);
  u16*    svhi   = (u16*)(ws + OFF_SVHI);
  u16*    svlo   = (u16*)(ws + OFF_SVLO);
  float*  svo    = (float*)(ws + OFF_SVO);
  int*    idxb   = (int*)(ws + OFF_IDX);
  float*  wgtb   = (float*)(ws + OFF_WGT);
  float*  logits = (float*)(ws + OFF_LOGITS);
  u16*    w1hi   = (u16*)(ws + OFF_W1HI);
  u16*    w1lo   = (u16*)(ws + OFF_W1LO);
  u16*    w2hi   = (u16*)(ws + OFF_W2HI);
  u16*    w2lo   = (u16*)(ws + OFF_W2LO);
  u16*    wihhi  = (u16*)(ws + OFF_WIHHI);
  u16*    wihlo  = (u16*)(ws + OFF_WIHLO);
  u16*    whhhi  = (u16*)(ws + OFF_WHHHI);
  u16*    whhlo  = (u16*)(ws + OFF_WHHLO);
  u16*    wvhi   = (u16*)(ws + OFF_WVHI);
  u16*    wvlo   = (u16*)(ws + OFF_WVLO);
  u16*    wohi   = (u16*)(ws + OFF_WOHI);
  u16*    wolo   = (u16*)(ws + OFF_WOLO);
  u16*    hhi    = (u16*)(ws + OFF_HHI);
  u16*    hlo    = (u16*)(ws + OFF_HLO);
  float*  dpart  = (float*)(ws + OFF_DPART);
  float*  dwsum  = (float*)(ws + OFF_DWSUM);
  double* hsmg   = (double*)(ws + OFF_HSMG);

  k_sniff<<<1, 64, 0, stream>>>((const u32*)w1, flag);

  k_init<<<64, 256, 0, stream>>>(sli, slsc, flag, m64, fcnt, hshi, hslo, hsf);
  k_b1p<<<2, 256, 0, stream>>>(w1, b1, flag, m64, b1p64, b1p32);

  // all weight hi/lo splits + all f32 bias conversions in ONE launch
  k_cvt_all<<<37025, 256, 0, stream>>>(w1, w2, wih, whh, wv, wo,
                                       b2, bih, bhh, bv, bo, ws, flag);

  // gh = hs @ whh^T + bhh   (64 x 3072)
  gemm_bt<0><<<dim3(1, 24), 512, 0, stream>>>(
      hshi, hslo, whhhi, whhlo, 64, 3072, 1024, 1024, bhhf, gh, nullptr, nullptr);

  // h = gelu(x @ w1a^T + b1') -> split  (16384 x 512), x split on the fly
  gemm_router<<<dim3(256, 4), 256, 0, stream>>>(
      x, w1hi, w1lo, NTOK, 512, 1024, 2048, b1p32, hhi, hlo, flag);

  // logits = h @ w2^T + b2   (16384 x 64)
  gemm_bt<0><<<dim3(128, 1), 512, 0, stream>>>(
      hhi, hlo, w2hi, w2lo, NTOK, 64, 512, 512, b2f, logits, nullptr, nullptr);

  k_topk<<<4096, 256, 0, stream>>>(logits, tau, flag, idxb, wgtb, fcnt, flags);
  k_repair_h<<<2048, 256, 0, stream>>>(x, w1, flag, b1p64, fcnt, flags, hsmg);
  k_repair_t<<<256, 256, 0, stream>>>(x, w1, w2, b2, tau, flag, b1p64, fcnt,
                                      flags, hsmg, idxb, wgtb);
  k_dispatch<<<2048, 256, 0, stream>>>(x, flag, idxb, wgtb, dpart, dwsum);
  k_dreduce<<<256, 256, 0, stream>>>(dpart, dwsum, gihi, gilo);

  // gx = gi @ wih^T + bih   (256 x 3072)
  gemm_bt<0><<<dim3(2, 24), 512, 0, stream>>>(
      gihi, gilo, wihhi, wihlo, 256, 3072, 1024, 1024, bihf, gx, nullptr, nullptr);

  k_gru<<<1024, 256, 0, stream>>>(gx, gh, hsf, snhi, snlo);

  // sv = S_new @ wv^T + bv  (256 x 1024) -> split
  gemm_bt<3><<<dim3(2, 8), 512, 0, stream>>>(
      snhi, snlo, wvhi, wvlo, 256, 1024, 1024, 1024, bvf, nullptr, svhi, svlo);

  // svo = sv @ wo^T + bo    (256 x 1024) -> f32
  gemm_bt<0><<<dim3(2, 8), 512, 0, stream>>>(
      svhi, svlo, wohi, wolo, 256, 1024, 1024, 1024, bof, svo, nullptr, nullptr);

  k_out<<<4096, 256, 0, stream>>>(idxb, wgtb, svo, flag, d_out);

  (void)in_sizes; (void)n_in; (void)out_size; (void)ws_size;
}